// Round 1
// baseline (29163.754 us; speedup 1.0000x reference)
//
#include <hip/hip_runtime.h>
#include <cmath>

#define V_ 50257
#define D_ 640
#define NL_ 16
#define DF_ 2560
#define R_ 24
#define DG_ 256
#define PLU_ 276
#define B_ 4
#define L_ 1024
#define M_ (B_*L_)
#define EPS_ 1e-6f
#define LN_EPS_ 1e-5f

#define TILE 64
#define BK 16

__device__ __forceinline__ float gelu_exact(float x) {
    return 0.5f * x * (1.0f + erff(x * 0.70710678118654752f));
}
__device__ __forceinline__ float sigmoid_f(float x) {
    return 1.0f / (1.0f + expf(-x));
}

// ---------------------------------------------------------------------------
// Generic tiled f32 GEMM: C[M,N] = act( (ACC ? C : 0) + mask * (A[M,K] . W[N,K]^T + bias) )
// W row stride = ldw (for gate sub-matrix views). delta>0 applies the causal
// row mask: rows with (row % L) < delta contribute zero.
// ---------------------------------------------------------------------------
template<int ACT, bool ACC>
__global__ __launch_bounds__(256) void gemm_k(
    const float* __restrict__ A, const float* __restrict__ W,
    const float* __restrict__ bias, float* __restrict__ C,
    int M, int N, int K, int ldw, int delta)
{
    __shared__ float As[TILE][BK + 1];
    __shared__ float Bs[TILE][BK + 1];
    const int bm = blockIdx.y * TILE;
    const int bn = blockIdx.x * TILE;
    const int tid = threadIdx.x;
    const int tx = tid & 15;
    const int ty = tid >> 4;
    const int lrow = tid >> 2;          // 0..63
    const int lcol = (tid & 3) << 2;    // 0,4,8,12

    float acc[4][4] = {};

    for (int k0 = 0; k0 < K; k0 += BK) {
        {   // A tile: 64 rows x 16 k
            float4 v = make_float4(0.f, 0.f, 0.f, 0.f);
            int gr = bm + lrow, gc = k0 + lcol;
            if (gr < M && gc < K)   // K % 4 == 0 always, so gc<K -> gc+3<K
                v = *reinterpret_cast<const float4*>(A + (size_t)gr * K + gc);
            As[lrow][lcol + 0] = v.x; As[lrow][lcol + 1] = v.y;
            As[lrow][lcol + 2] = v.z; As[lrow][lcol + 3] = v.w;
        }
        {   // W tile: 64 n-rows x 16 k
            float4 v = make_float4(0.f, 0.f, 0.f, 0.f);
            int gr = bn + lrow, gc = k0 + lcol;
            if (gr < N && gc < K)
                v = *reinterpret_cast<const float4*>(W + (size_t)gr * ldw + gc);
            Bs[lrow][lcol + 0] = v.x; Bs[lrow][lcol + 1] = v.y;
            Bs[lrow][lcol + 2] = v.z; Bs[lrow][lcol + 3] = v.w;
        }
        __syncthreads();
        #pragma unroll
        for (int k = 0; k < BK; ++k) {
            float a0 = As[ty * 4 + 0][k], a1 = As[ty * 4 + 1][k];
            float a2 = As[ty * 4 + 2][k], a3 = As[ty * 4 + 3][k];
            float b0 = Bs[tx * 4 + 0][k], b1 = Bs[tx * 4 + 1][k];
            float b2 = Bs[tx * 4 + 2][k], b3 = Bs[tx * 4 + 3][k];
            acc[0][0] += a0 * b0; acc[0][1] += a0 * b1; acc[0][2] += a0 * b2; acc[0][3] += a0 * b3;
            acc[1][0] += a1 * b0; acc[1][1] += a1 * b1; acc[1][2] += a1 * b2; acc[1][3] += a1 * b3;
            acc[2][0] += a2 * b0; acc[2][1] += a2 * b1; acc[2][2] += a2 * b2; acc[2][3] += a2 * b3;
            acc[3][0] += a3 * b0; acc[3][1] += a3 * b1; acc[3][2] += a3 * b2; acc[3][3] += a3 * b3;
        }
        __syncthreads();
    }

    #pragma unroll
    for (int i = 0; i < 4; ++i) {
        int row = bm + ty * 4 + i;
        if (row >= M) continue;
        bool masked = (delta > 0) && ((row & (L_ - 1)) < delta);
        #pragma unroll
        for (int j = 0; j < 4; ++j) {
            int col = bn + tx * 4 + j;
            if (col >= N) continue;
            float contrib = acc[i][j] + (bias ? bias[col] : 0.0f);
            if (masked) contrib = 0.0f;
            float out = ACC ? (C[(size_t)row * N + col] + contrib) : contrib;
            if (ACT == 1) out = gelu_exact(out);
            else if (ACT == 2) out = sigmoid_f(out);
            C[(size_t)row * N + col] = out;
        }
    }
}

// ---------------------------------------------------------------------------
// x = tok_emb[ids] + pos_emb[l]
// ---------------------------------------------------------------------------
__global__ __launch_bounds__(256) void embed_k(
    const int* __restrict__ ids, const float* __restrict__ tok,
    const float* __restrict__ pos, float* __restrict__ x)
{
    int idx = blockIdx.x * 256 + threadIdx.x;
    if (idx >= M_ * D_) return;
    int row = idx / D_;
    int d = idx - row * D_;
    int l = row & (L_ - 1);
    x[idx] = tok[(size_t)ids[row] * D_ + d] + pos[(size_t)l * D_ + d];
}

// ---------------------------------------------------------------------------
// LayerNorm: one block (128 threads) per row of D=640
// ---------------------------------------------------------------------------
__global__ __launch_bounds__(128) void ln_k(
    const float* __restrict__ x, const float* __restrict__ w,
    const float* __restrict__ b, float* __restrict__ out)
{
    int row = blockIdx.x;
    int tid = threadIdx.x;
    const float* xr = x + (size_t)row * D_;
    float v[5];
    float sum = 0.f, sumsq = 0.f;
    #pragma unroll
    for (int t = 0; t < 5; ++t) {
        v[t] = xr[tid + t * 128];
        sum += v[t]; sumsq += v[t] * v[t];
    }
    #pragma unroll
    for (int off = 32; off > 0; off >>= 1) {
        sum += __shfl_down(sum, off);
        sumsq += __shfl_down(sumsq, off);
    }
    __shared__ float s0[2], s1[2];
    if ((tid & 63) == 0) { s0[tid >> 6] = sum; s1[tid >> 6] = sumsq; }
    __syncthreads();
    float m = (s0[0] + s1[0] * 0.f + s0[1]) * (1.0f / D_);
    float var = (s1[0] + s1[1]) * (1.0f / D_) - m * m;
    float inv = rsqrtf(var + LN_EPS_);
    #pragma unroll
    for (int t = 0; t < 5; ++t) {
        int d = tid + t * 128;
        out[(size_t)row * D_ + d] = (v[t] - m) * inv * w[d] + b[d];
    }
}

// ---------------------------------------------------------------------------
// Plucker coords for one delta: one block (128 threads) per (b,l) row.
// p[row, idx] = normalize( zp[i]*zc[j] - zp[j]*zc[i] ), zero if l < delta
// ---------------------------------------------------------------------------
__global__ __launch_bounds__(128) void plucker_k(
    const float* __restrict__ z, float* __restrict__ p, int delta)
{
    int row = blockIdx.x;
    int l = row & (L_ - 1);
    int tid = threadIdx.x;
    if (l < delta) {
        for (int idx = tid; idx < PLU_; idx += 128)
            p[(size_t)row * PLU_ + idx] = 0.f;
        return;
    }
    __shared__ float zc[R_], zp[R_];
    if (tid < R_) {
        zc[tid] = z[(size_t)row * R_ + tid];
        zp[tid] = z[(size_t)(row - delta) * R_ + tid];
    }
    __syncthreads();
    float vals[3];
    float ss = 0.f;
    #pragma unroll
    for (int t = 0; t < 3; ++t) {
        int idx = tid + t * 128;
        float val = 0.f;
        if (idx < PLU_) {
            int i = 0, rem = idx;
            while (rem >= 23 - i) { rem -= 23 - i; ++i; }
            int j = i + 1 + rem;
            val = zp[i] * zc[j] - zp[j] * zc[i];
        }
        vals[t] = val;
        ss += val * val;
    }
    #pragma unroll
    for (int off = 32; off > 0; off >>= 1) ss += __shfl_down(ss, off);
    __shared__ float wsum[2];
    if ((tid & 63) == 0) wsum[tid >> 6] = ss;
    __syncthreads();
    float inv = 1.0f / fmaxf(sqrtf(wsum[0] + wsum[1]), EPS_);
    #pragma unroll
    for (int t = 0; t < 3; ++t) {
        int idx = tid + t * 128;
        if (idx < PLU_) p[(size_t)row * PLU_ + idx] = vals[t] * inv;
    }
}

// ---------------------------------------------------------------------------
// g = geom_sum / max(count(l), 1)
// ---------------------------------------------------------------------------
__global__ __launch_bounds__(256) void gavg_k(float* __restrict__ g)
{
    int idx = blockIdx.x * 256 + threadIdx.x;
    if (idx >= M_ * D_) return;
    int row = idx / D_;
    int l = row & (L_ - 1);
    int cnt = (l >= 1) + (l >= 2) + (l >= 4) + (l >= 8) + (l >= 16) + (l >= 32) + (l >= 64);
    g[idx] *= 1.0f / (float)max(cnt, 1);
}

// ---------------------------------------------------------------------------
// x = x + alpha*h + (1-alpha)*g
// ---------------------------------------------------------------------------
__global__ __launch_bounds__(256) void xupd_k(
    float* __restrict__ x, const float* __restrict__ h,
    const float* __restrict__ g, const float* __restrict__ al)
{
    int idx = blockIdx.x * 256 + threadIdx.x;
    if (idx >= M_ * D_) return;
    float a = al[idx];
    x[idx] = x[idx] + a * h[idx] + (1.0f - a) * g[idx];
}

// ---------------------------------------------------------------------------
static void gemm(int act, bool accf, const float* A, const float* W,
                 const float* bias, float* C, int M, int N, int K, int ldw,
                 int delta, hipStream_t s)
{
    dim3 grid((N + TILE - 1) / TILE, (M + TILE - 1) / TILE), block(256);
    if (act == 0 && !accf)      gemm_k<0, false><<<grid, block, 0, s>>>(A, W, bias, C, M, N, K, ldw, delta);
    else if (act == 0 && accf)  gemm_k<0, true ><<<grid, block, 0, s>>>(A, W, bias, C, M, N, K, ldw, delta);
    else if (act == 1)          gemm_k<1, false><<<grid, block, 0, s>>>(A, W, bias, C, M, N, K, ldw, delta);
    else                        gemm_k<2, true ><<<grid, block, 0, s>>>(A, W, bias, C, M, N, K, ldw, delta);
}

extern "C" void kernel_launch(void* const* d_in, const int* in_sizes, int n_in,
                              void* d_out, int out_size, void* d_ws, size_t ws_size,
                              hipStream_t stream)
{
    const int*   ids   = (const int*)d_in[0];
    const float* tok   = (const float*)d_in[1];
    const float* pos   = (const float*)d_in[2];
    const float* ln1w  = (const float*)d_in[3];
    const float* ln1b  = (const float*)d_in[4];
    const float* redw  = (const float*)d_in[5];
    const float* redb  = (const float*)d_in[6];
    const float* gp1w  = (const float*)d_in[7];
    const float* gp1b  = (const float*)d_in[8];
    const float* gp2w  = (const float*)d_in[9];
    const float* gp2b  = (const float*)d_in[10];
    const float* gatew = (const float*)d_in[11];
    const float* gateb = (const float*)d_in[12];
    const float* ln2w  = (const float*)d_in[13];
    const float* ln2b  = (const float*)d_in[14];
    const float* fc1w  = (const float*)d_in[15];
    const float* fc1b  = (const float*)d_in[16];
    const float* fc2w  = (const float*)d_in[17];
    const float* fc2b  = (const float*)d_in[18];
    const float* fnw   = (const float*)d_in[19];
    const float* fnb   = (const float*)d_in[20];
    float* out = (float*)d_out;

    float* ws = (float*)d_ws;
    const size_t MD = (size_t)M_ * D_;
    float* x  = ws;
    float* h  = x + MD;
    float* g  = h + MD;
    float* al = g + MD;
    float* z  = al + MD;
    float* p  = z + (size_t)M_ * R_;
    float* c1 = p + (size_t)M_ * PLU_;
    float* ff = c1 + (size_t)M_ * DG_;

    const int ELT_GRID = (M_ * D_ + 255) / 256;

    embed_k<<<ELT_GRID, 256, 0, stream>>>(ids, tok, pos, x);

    static const int offs[7] = {1, 2, 4, 8, 16, 32, 64};
    for (int l = 0; l < NL_; ++l) {
        ln_k<<<M_, 128, 0, stream>>>(x, ln1w + (size_t)l * D_, ln1b + (size_t)l * D_, h);
        gemm(0, false, h, redw + (size_t)l * R_ * D_, redb + (size_t)l * R_, z,
             M_, R_, D_, D_, 0, stream);
        for (int oi = 0; oi < 7; ++oi) {
            int delta = offs[oi];
            plucker_k<<<M_, 128, 0, stream>>>(z, p, delta);
            gemm(1, false, p, gp1w + (size_t)l * DG_ * PLU_, gp1b + (size_t)l * DG_, c1,
                 M_, DG_, PLU_, PLU_, 0, stream);
            gemm(0, oi != 0, c1, gp2w + (size_t)l * D_ * DG_, gp2b + (size_t)l * D_, g,
                 M_, D_, DG_, DG_, delta, stream);
        }
        gavg_k<<<ELT_GRID, 256, 0, stream>>>(g);
        gemm(0, false, h, gatew + (size_t)l * D_ * 2 * D_, gateb + (size_t)l * D_, al,
             M_, D_, D_, 2 * D_, 0, stream);
        gemm(2, true, g, gatew + (size_t)l * D_ * 2 * D_ + D_, nullptr, al,
             M_, D_, D_, 2 * D_, 0, stream);
        xupd_k<<<ELT_GRID, 256, 0, stream>>>(x, h, g, al);
        ln_k<<<M_, 128, 0, stream>>>(x, ln2w + (size_t)l * D_, ln2b + (size_t)l * D_, h);
        gemm(1, false, h, fc1w + (size_t)l * DF_ * D_, fc1b + (size_t)l * DF_, ff,
             M_, DF_, D_, D_, 0, stream);
        gemm(0, true, ff, fc2w + (size_t)l * D_ * DF_, fc2b + (size_t)l * D_, x,
             M_, D_, DF_, DF_, 0, stream);
    }
    ln_k<<<M_, 128, 0, stream>>>(x, fnw, fnb, h);
    gemm(0, false, h, tok, nullptr, out, M_, V_, D_, D_, 0, stream);
}

// Round 2
// 5890.314 us; speedup vs baseline: 4.9511x; 4.9511x over previous
//
#include <hip/hip_runtime.h>
#include <cmath>

#define V_ 50257
#define D_ 640
#define NL_ 16
#define DF_ 2560
#define R_ 24
#define DG_ 256
#define PLU_ 276
#define PLUP_ 288
#define B_ 4
#define L_ 1024
#define M_ (B_*L_)
#define EPS_ 1e-6f
#define LN_EPS_ 1e-5f

typedef __bf16 bf16x8 __attribute__((ext_vector_type(8)));
typedef float f32x4 __attribute__((ext_vector_type(4)));

__device__ __forceinline__ float gelu_exact(float x) {
    return 0.5f * x * (1.0f + erff(x * 0.70710678118654752f));
}
__device__ __forceinline__ float sigmoid_f(float x) {
    return 1.0f / (1.0f + expf(-x));
}
__device__ __forceinline__ ushort f2b(float f) {
    union { float f; unsigned u; } v; v.f = f;
    unsigned u = v.u;
    return (ushort)((u + 0x7FFFu + ((u >> 16) & 1u)) >> 16);
}

#define GLOAD16(gptr, lptr) \
    __builtin_amdgcn_global_load_lds((const __attribute__((address_space(1))) void*)(gptr), \
                                     (__attribute__((address_space(3))) void*)(lptr), 16, 0, 0)

// ---------------------------------------------------------------------------
// MFMA bf16 GEMM: C[M,N] = act( (ACC?C:0) + A[M,K]·W[N,K]^T + bias )
// 128x128 tile, 4 waves, each wave 64x64 via 4x4 fragments of 16x16x32.
// M must be a multiple of 128; K a multiple of 32; N arbitrary (clamped loads).
// ---------------------------------------------------------------------------
template<int ACT, bool ACC, bool OUTB>
__global__ __launch_bounds__(256) void mgemm_k(
    const ushort* __restrict__ A, const ushort* __restrict__ W,
    const float* __restrict__ bias, float* __restrict__ Cf,
    ushort* __restrict__ Cb, int M, int N, int K)
{
    __shared__ ushort As[128 * 32];
    __shared__ ushort Bs[128 * 32];
    const int tid = threadIdx.x;
    const int lane = tid & 63;
    const int w = tid >> 6;
    const int wr = w >> 1, wc = w & 1;
    const int lr = lane & 15, lk = lane >> 4;
    const int bm = blockIdx.y * 128, bn = blockIdx.x * 128;
    const int srow = lane >> 2;          // 0..15 within a 16-row chunk
    const int scol = (lane & 3) * 8;     // k-offset in elements (16B chunks)

    f32x4 acc[4][4] = {};

    for (int k0 = 0; k0 < K; k0 += 32) {
        #pragma unroll
        for (int i = 0; i < 2; ++i) {
            int r = w * 32 + i * 16 + srow;
            const ushort* ga = A + (size_t)(bm + r) * K + (k0 + scol);
            GLOAD16(ga, &As[(w * 32 + i * 16) * 32]);
        }
        #pragma unroll
        for (int i = 0; i < 2; ++i) {
            int r = bn + w * 32 + i * 16 + srow;
            if (r > N - 1) r = N - 1;   // clamp for ragged N (lm_head)
            const ushort* gb = W + (size_t)r * K + (k0 + scol);
            GLOAD16(gb, &Bs[(w * 32 + i * 16) * 32]);
        }
        __syncthreads();
        bf16x8 af[4], bfr[4];
        #pragma unroll
        for (int m = 0; m < 4; ++m)
            af[m] = *reinterpret_cast<const bf16x8*>(&As[(wr * 64 + m * 16 + lr) * 32 + lk * 8]);
        #pragma unroll
        for (int n = 0; n < 4; ++n)
            bfr[n] = *reinterpret_cast<const bf16x8*>(&Bs[(wc * 64 + n * 16 + lr) * 32 + lk * 8]);
        #pragma unroll
        for (int m = 0; m < 4; ++m)
            #pragma unroll
            for (int n = 0; n < 4; ++n)
                acc[m][n] = __builtin_amdgcn_mfma_f32_16x16x32_bf16(af[m], bfr[n], acc[m][n], 0, 0, 0);
        __syncthreads();
    }

    #pragma unroll
    for (int n = 0; n < 4; ++n) {
        int col = bn + wc * 64 + n * 16 + lr;
        if (col >= N) continue;
        float bsv = bias ? bias[col] : 0.0f;
        #pragma unroll
        for (int m = 0; m < 4; ++m) {
            #pragma unroll
            for (int r = 0; r < 4; ++r) {
                int row = bm + wr * 64 + m * 16 + lk * 4 + r;
                float o = acc[m][n][r] + bsv;
                if (ACC) o += Cf[(size_t)row * N + col];
                if (ACT == 1) o = gelu_exact(o);
                else if (ACT == 2) o = sigmoid_f(o);
                if (OUTB) Cb[(size_t)row * N + col] = f2b(o);
                else      Cf[(size_t)row * N + col] = o;
            }
        }
    }
}

// ---------------------------------------------------------------------------
// Small f32 GEMM (red projection only, N=24): C = A[M,K]·W[N,K]^T + bias
// ---------------------------------------------------------------------------
#define TILE 64
#define BK 16
__global__ __launch_bounds__(256) void gemm_f32_k(
    const float* __restrict__ A, const float* __restrict__ W,
    const float* __restrict__ bias, float* __restrict__ C,
    int M, int N, int K)
{
    __shared__ float As[TILE][BK + 1];
    __shared__ float Bs[TILE][BK + 1];
    const int bm = blockIdx.y * TILE;
    const int bn = blockIdx.x * TILE;
    const int tid = threadIdx.x;
    const int tx = tid & 15;
    const int ty = tid >> 4;
    const int lrow = tid >> 2;
    const int lcol = (tid & 3) << 2;

    float acc[4][4] = {};

    for (int k0 = 0; k0 < K; k0 += BK) {
        {
            float4 v = make_float4(0.f, 0.f, 0.f, 0.f);
            int gr = bm + lrow, gc = k0 + lcol;
            if (gr < M && gc < K)
                v = *reinterpret_cast<const float4*>(A + (size_t)gr * K + gc);
            As[lrow][lcol + 0] = v.x; As[lrow][lcol + 1] = v.y;
            As[lrow][lcol + 2] = v.z; As[lrow][lcol + 3] = v.w;
        }
        {
            float4 v = make_float4(0.f, 0.f, 0.f, 0.f);
            int gr = bn + lrow, gc = k0 + lcol;
            if (gr < N && gc < K)
                v = *reinterpret_cast<const float4*>(W + (size_t)gr * K + gc);
            Bs[lrow][lcol + 0] = v.x; Bs[lrow][lcol + 1] = v.y;
            Bs[lrow][lcol + 2] = v.z; Bs[lrow][lcol + 3] = v.w;
        }
        __syncthreads();
        #pragma unroll
        for (int k = 0; k < BK; ++k) {
            float a0 = As[ty * 4 + 0][k], a1 = As[ty * 4 + 1][k];
            float a2 = As[ty * 4 + 2][k], a3 = As[ty * 4 + 3][k];
            float b0 = Bs[tx * 4 + 0][k], b1 = Bs[tx * 4 + 1][k];
            float b2 = Bs[tx * 4 + 2][k], b3 = Bs[tx * 4 + 3][k];
            acc[0][0] += a0 * b0; acc[0][1] += a0 * b1; acc[0][2] += a0 * b2; acc[0][3] += a0 * b3;
            acc[1][0] += a1 * b0; acc[1][1] += a1 * b1; acc[1][2] += a1 * b2; acc[1][3] += a1 * b3;
            acc[2][0] += a2 * b0; acc[2][1] += a2 * b1; acc[2][2] += a2 * b2; acc[2][3] += a2 * b3;
            acc[3][0] += a3 * b0; acc[3][1] += a3 * b1; acc[3][2] += a3 * b2; acc[3][3] += a3 * b3;
        }
        __syncthreads();
    }
    #pragma unroll
    for (int i = 0; i < 4; ++i) {
        int row = bm + ty * 4 + i;
        if (row >= M) continue;
        #pragma unroll
        for (int j = 0; j < 4; ++j) {
            int col = bn + tx * 4 + j;
            if (col >= N) continue;
            C[(size_t)row * N + col] = acc[i][j] + (bias ? bias[col] : 0.0f);
        }
    }
}

// ---------------------------------------------------------------------------
__global__ __launch_bounds__(256) void embed_k(
    const int* __restrict__ ids, const float* __restrict__ tok,
    const float* __restrict__ pos, float* __restrict__ x)
{
    int idx = blockIdx.x * 256 + threadIdx.x;
    if (idx >= M_ * D_) return;
    int row = idx / D_;
    int d = idx - row * D_;
    int l = row & (L_ - 1);
    x[idx] = tok[(size_t)ids[row] * D_ + d] + pos[(size_t)l * D_ + d];
}

// f32 -> bf16 bulk convert
__global__ __launch_bounds__(256) void cvt_k(
    const float* __restrict__ src, ushort* __restrict__ dst, int n)
{
    int idx = blockIdx.x * 256 + threadIdx.x;
    if (idx < n) dst[idx] = f2b(src[idx]);
}

// per-layer weight conversion (gp1 padded 276->288, gp2, gate, fc1, fc2)
#define WC_G1  73728
#define WC_G2  (WC_G1 + 163840)
#define WC_GT  (WC_G2 + 819200)
#define WC_F1  (WC_GT + 1638400)
#define WC_F2  (WC_F1 + 1638400)
__global__ __launch_bounds__(256) void wconv_k(
    const float* __restrict__ g1, const float* __restrict__ g2,
    const float* __restrict__ gt, const float* __restrict__ f1,
    const float* __restrict__ f2, ushort* __restrict__ wb)
{
    int idx = blockIdx.x * 256 + threadIdx.x;
    if (idx < WC_G1) {
        int row = idx / PLUP_, c = idx - row * PLUP_;
        wb[idx] = (c < PLU_) ? f2b(g1[row * PLU_ + c]) : (ushort)0;
    } else if (idx < WC_G2) {
        wb[idx] = f2b(g2[idx - WC_G1]);
    } else if (idx < WC_GT) {
        wb[idx] = f2b(gt[idx - WC_G2]);
    } else if (idx < WC_F1) {
        wb[idx] = f2b(f1[idx - WC_GT]);
    } else if (idx < WC_F2) {
        wb[idx] = f2b(f2[idx - WC_F1]);
    }
}

// ---------------------------------------------------------------------------
// LayerNorm, one block (128 threads) per row. Optional f32 out + bf16 out.
// ---------------------------------------------------------------------------
__global__ __launch_bounds__(128) void ln_k(
    const float* __restrict__ x, const float* __restrict__ w,
    const float* __restrict__ b, float* __restrict__ outf,
    ushort* __restrict__ outb, int bstride)
{
    int row = blockIdx.x;
    int tid = threadIdx.x;
    const float* xr = x + (size_t)row * D_;
    float v[5];
    float sum = 0.f, sumsq = 0.f;
    #pragma unroll
    for (int t = 0; t < 5; ++t) {
        v[t] = xr[tid + t * 128];
        sum += v[t]; sumsq += v[t] * v[t];
    }
    #pragma unroll
    for (int off = 32; off > 0; off >>= 1) {
        sum += __shfl_down(sum, off);
        sumsq += __shfl_down(sumsq, off);
    }
    __shared__ float s0[2], s1[2];
    if ((tid & 63) == 0) { s0[tid >> 6] = sum; s1[tid >> 6] = sumsq; }
    __syncthreads();
    float m = (s0[0] + s0[1]) * (1.0f / D_);
    float var = (s1[0] + s1[1]) * (1.0f / D_) - m * m;
    float inv = rsqrtf(var + LN_EPS_);
    #pragma unroll
    for (int t = 0; t < 5; ++t) {
        int d = tid + t * 128;
        float o = (v[t] - m) * inv * w[d] + b[d];
        if (outf) outf[(size_t)row * D_ + d] = o;
        if (outb) outb[(size_t)row * bstride + d] = f2b(o);
    }
}

// ---------------------------------------------------------------------------
// Plucker for all 7 deltas: grid (M_, 7). Writes bf16 padded to 288.
// ---------------------------------------------------------------------------
__global__ __launch_bounds__(128) void plucker7_k(
    const float* __restrict__ z, ushort* __restrict__ pb)
{
    int oi = blockIdx.y;
    int delta = 1 << oi;
    int row = blockIdx.x;
    int l = row & (L_ - 1);
    int tid = threadIdx.x;
    ushort* out = pb + ((size_t)oi * M_ + row) * PLUP_;
    if (l < delta) {
        for (int idx = tid; idx < PLUP_; idx += 128) out[idx] = 0;
        return;
    }
    __shared__ float zc[R_], zp[R_];
    if (tid < R_) {
        zc[tid] = z[(size_t)row * R_ + tid];
        zp[tid] = z[(size_t)(row - delta) * R_ + tid];
    }
    __syncthreads();
    float vals[3];
    float ss = 0.f;
    #pragma unroll
    for (int t = 0; t < 3; ++t) {
        int idx = tid + t * 128;
        float val = 0.f;
        if (idx < PLU_) {
            int i = 0, rem = idx;
            while (rem >= 23 - i) { rem -= 23 - i; ++i; }
            int j = i + 1 + rem;
            val = zp[i] * zc[j] - zp[j] * zc[i];
        }
        vals[t] = val;
        ss += val * val;
    }
    #pragma unroll
    for (int off = 32; off > 0; off >>= 1) ss += __shfl_down(ss, off);
    __shared__ float wsum[2];
    if ((tid & 63) == 0) wsum[tid >> 6] = ss;
    __syncthreads();
    float inv = 1.0f / fmaxf(sqrtf(wsum[0] + wsum[1]), EPS_);
    #pragma unroll
    for (int t = 0; t < 3; ++t) {
        int idx = tid + t * 128;
        if (idx < PLUP_) out[idx] = (idx < PLU_) ? f2b(vals[t] * inv) : (ushort)0;
    }
}

// ---------------------------------------------------------------------------
// g = (sum over deltas of masked gbig) / max(count,1); writes f32 g + bf16 hg
// ---------------------------------------------------------------------------
__global__ __launch_bounds__(256) void greduce_k(
    const float* __restrict__ gbig, float* __restrict__ g,
    ushort* __restrict__ hgb)
{
    int idx = blockIdx.x * 256 + threadIdx.x;
    if (idx >= M_ * D_) return;
    int row = idx / D_;
    int d = idx - row * D_;
    int l = row & (L_ - 1);
    float s = 0.f;
    int c = 0;
    #pragma unroll
    for (int oi = 0; oi < 7; ++oi) {
        if (l >= (1 << oi)) {
            s += gbig[(size_t)oi * M_ * D_ + idx];
            ++c;
        }
    }
    float gv = s / (float)max(c, 1);
    g[idx] = gv;
    hgb[(size_t)row * (2 * D_) + D_ + d] = f2b(gv);
}

// ---------------------------------------------------------------------------
__global__ __launch_bounds__(256) void xupd_k(
    float* __restrict__ x, const float* __restrict__ h,
    const float* __restrict__ g, const float* __restrict__ al)
{
    int idx = blockIdx.x * 256 + threadIdx.x;
    if (idx >= M_ * D_) return;
    float a = al[idx];
    x[idx] = x[idx] + a * h[idx] + (1.0f - a) * g[idx];
}

// ---------------------------------------------------------------------------
static void mgemm(int act, bool accf, bool outb, const ushort* A, const ushort* W,
                  const float* bias, float* Cf, ushort* Cb, int M, int N, int K,
                  hipStream_t s)
{
    dim3 grid((N + 127) / 128, M / 128), block(256);
    if (outb) {
        mgemm_k<1, false, true><<<grid, block, 0, s>>>(A, W, bias, Cf, Cb, M, N, K);
    } else if (accf) {
        mgemm_k<0, true, false><<<grid, block, 0, s>>>(A, W, bias, Cf, Cb, M, N, K);
    } else if (act == 2) {
        mgemm_k<2, false, false><<<grid, block, 0, s>>>(A, W, bias, Cf, Cb, M, N, K);
    } else {
        mgemm_k<0, false, false><<<grid, block, 0, s>>>(A, W, bias, Cf, Cb, M, N, K);
    }
}

extern "C" void kernel_launch(void* const* d_in, const int* in_sizes, int n_in,
                              void* d_out, int out_size, void* d_ws, size_t ws_size,
                              hipStream_t stream)
{
    const int*   ids   = (const int*)d_in[0];
    const float* tok   = (const float*)d_in[1];
    const float* pos   = (const float*)d_in[2];
    const float* ln1w  = (const float*)d_in[3];
    const float* ln1b  = (const float*)d_in[4];
    const float* redw  = (const float*)d_in[5];
    const float* redb  = (const float*)d_in[6];
    const float* gp1w  = (const float*)d_in[7];
    const float* gp1b  = (const float*)d_in[8];
    const float* gp2w  = (const float*)d_in[9];
    const float* gp2b  = (const float*)d_in[10];
    const float* gatew = (const float*)d_in[11];
    const float* gateb = (const float*)d_in[12];
    const float* ln2w  = (const float*)d_in[13];
    const float* ln2b  = (const float*)d_in[14];
    const float* fc1w  = (const float*)d_in[15];
    const float* fc1b  = (const float*)d_in[16];
    const float* fc2w  = (const float*)d_in[17];
    const float* fc2b  = (const float*)d_in[18];
    const float* fnw   = (const float*)d_in[19];
    const float* fnb   = (const float*)d_in[20];
    float* out = (float*)d_out;

    const size_t MD = (size_t)M_ * D_;
    float* ws = (float*)d_ws;
    float* x    = ws;                    // MD
    float* h    = x + MD;                // MD
    float* g    = h + MD;                // MD
    float* al   = g + MD;                // MD
    float* z    = al + MD;               // M_*R_
    float* gbig = z + (size_t)M_ * R_;   // 7*MD
    ushort* bb  = (ushort*)(gbig + 7 * MD);
    ushort* pb   = bb;                                    // 7*M_*288
    ushort* c1b  = pb  + (size_t)7 * M_ * PLUP_;          // 7*M_*256
    ushort* hgb  = c1b + (size_t)7 * M_ * DG_;            // M_*1280
    ushort* h2b  = hgb + (size_t)M_ * 2 * D_;             // M_*640
    ushort* ffb  = h2b + MD;                              // M_*2560
    ushort* xnb  = ffb + (size_t)M_ * DF_;                // M_*640
    ushort* tokb = xnb + MD;                              // V_*640
    ushort* wb   = tokb + (size_t)V_ * D_;                // 4,333,568

    const int ELT_GRID = (M_ * D_ + 255) / 256;

    embed_k<<<ELT_GRID, 256, 0, stream>>>(ids, tok, pos, x);
    cvt_k<<<(V_ * D_ + 255) / 256, 256, 0, stream>>>(tok, tokb, V_ * D_);

    for (int l = 0; l < NL_; ++l) {
        wconv_k<<<(WC_F2 + 255) / 256, 256, 0, stream>>>(
            gp1w + (size_t)l * DG_ * PLU_, gp2w + (size_t)l * D_ * DG_,
            gatew + (size_t)l * D_ * 2 * D_, fc1w + (size_t)l * DF_ * D_,
            fc2w + (size_t)l * D_ * DF_, wb);
        ln_k<<<M_, 128, 0, stream>>>(x, ln1w + (size_t)l * D_, ln1b + (size_t)l * D_,
                                     h, hgb, 2 * D_);
        {   // red projection (f32, tiny)
            dim3 grid((R_ + TILE - 1) / TILE, (M_ + TILE - 1) / TILE), block(256);
            gemm_f32_k<<<grid, block, 0, stream>>>(h, redw + (size_t)l * R_ * D_,
                                                   redb + (size_t)l * R_, z, M_, R_, D_);
        }
        plucker7_k<<<dim3(M_, 7), 128, 0, stream>>>(z, pb);
        mgemm(1, false, true, pb, wb, gp1b + (size_t)l * DG_, nullptr, c1b,
              7 * M_, DG_, PLUP_, stream);
        mgemm(0, false, false, c1b, wb + WC_G1, gp2b + (size_t)l * D_, gbig, nullptr,
              7 * M_, D_, DG_, stream);
        greduce_k<<<ELT_GRID, 256, 0, stream>>>(gbig, g, hgb);
        mgemm(2, false, false, hgb, wb + WC_G2, gateb + (size_t)l * D_, al, nullptr,
              M_, D_, 2 * D_, stream);
        xupd_k<<<ELT_GRID, 256, 0, stream>>>(x, h, g, al);
        ln_k<<<M_, 128, 0, stream>>>(x, ln2w + (size_t)l * D_, ln2b + (size_t)l * D_,
                                     nullptr, h2b, D_);
        mgemm(1, false, true, h2b, wb + WC_GT, fc1b + (size_t)l * DF_, nullptr, ffb,
              M_, DF_, D_, stream);
        mgemm(0, true, false, ffb, wb + WC_F1, fc2b + (size_t)l * D_, x, nullptr,
              M_, D_, DF_, stream);
    }
    ln_k<<<M_, 128, 0, stream>>>(x, fnw, fnb, nullptr, xnb, D_);
    mgemm(0, false, false, xnb, tokb, nullptr, out, nullptr, M_, V_, D_, stream);
}

// Round 3
// 4851.707 us; speedup vs baseline: 6.0110x; 1.2141x over previous
//
#include <hip/hip_runtime.h>
#include <cmath>

#define V_ 50257
#define D_ 640
#define NL_ 16
#define DF_ 2560
#define R_ 24
#define DG_ 256
#define PLU_ 276
#define PLUP_ 288
#define B_ 4
#define L_ 1024
#define M_ (B_*L_)
#define EPS_ 1e-6f
#define LN_EPS_ 1e-5f

typedef __bf16 bf16x8 __attribute__((ext_vector_type(8)));
typedef float f32x4 __attribute__((ext_vector_type(4)));

__device__ __forceinline__ float gelu_exact(float x) {
    return 0.5f * x * (1.0f + erff(x * 0.70710678118654752f));
}
__device__ __forceinline__ float sigmoid_f(float x) {
    return 1.0f / (1.0f + expf(-x));
}
__device__ __forceinline__ ushort f2b(float f) {
    union { float f; unsigned u; } v; v.f = f;
    unsigned u = v.u;
    return (ushort)((u + 0x7FFFu + ((u >> 16) & 1u)) >> 16);
}
__device__ __forceinline__ float b2f(ushort b) {
    union { unsigned u; float f; } v; v.u = ((unsigned)b) << 16;
    return v.f;
}

#define GLOAD16(gptr, lptr) \
    __builtin_amdgcn_global_load_lds((const __attribute__((address_space(1))) void*)(gptr), \
                                     (__attribute__((address_space(3))) void*)(lptr), 16, 0, 0)

// EPI: 0 = f32 out; 1 = gelu -> bf16 out; 2 = gate-fused x-update; 3 = f32 accumulate; 4 = bf16 out
// LDS layout: row-major [rows][32] bf16 (64B rows), XOR-swizzled: LDS[r][c] holds
// global chunk c ^ ((r>>1)&3) (16B chunks). Staging pre-swizzles the GLOBAL source
// (global_load_lds dest must stay linear, m104/m173); ds_read applies the same XOR.
// Post-swizzle each quarter-wave's 16 ds_read_b128 spread over all 8 bank groups (2-way, free).

// ---------------------------------------------------------------------------
// 128x128 tile, 4 waves (2x2), each wave 64x64 = 4x4 frags of 16x16x32.
// Grid: (M/128, ceil(N/128)) -- M-blocks vary FASTEST (W-tile L2 reuse).
// ---------------------------------------------------------------------------
template<int EPI>
__global__ __launch_bounds__(256) void mgemm128_k(
    const ushort* __restrict__ A, const ushort* __restrict__ W,
    const float* __restrict__ bias, float* __restrict__ Cf,
    ushort* __restrict__ Cb, int M, int N, int K)
{
    __shared__ ushort As[128 * 32];
    __shared__ ushort Bs[128 * 32];
    const int tid = threadIdx.x;
    const int lane = tid & 63;
    const int w = tid >> 6;
    const int wr = w >> 1, wc = w & 1;
    const int lr = lane & 15, lk = lane >> 4;
    const int bm = blockIdx.x * 128, bn = blockIdx.y * 128;
    const int srow = lane >> 2;
    const int scol = (((lane & 3) ^ ((srow >> 1) & 3)) * 8);  // swizzled source chunk

    f32x4 acc[4][4] = {};

    for (int k0 = 0; k0 < K; k0 += 32) {
        #pragma unroll
        for (int i = 0; i < 2; ++i) {
            int r = w * 32 + i * 16 + srow;
            GLOAD16(A + (size_t)(bm + r) * K + (k0 + scol), &As[(w * 32 + i * 16) * 32]);
        }
        #pragma unroll
        for (int i = 0; i < 2; ++i) {
            int r = bn + w * 32 + i * 16 + srow;
            if (r > N - 1) r = N - 1;   // clamp for ragged N (lm_head)
            GLOAD16(W + (size_t)r * K + (k0 + scol), &Bs[(w * 32 + i * 16) * 32]);
        }
        __syncthreads();
        bf16x8 af[4], bfr[4];
        #pragma unroll
        for (int m = 0; m < 4; ++m) {
            int r = wr * 64 + m * 16 + lr;
            af[m] = *reinterpret_cast<const bf16x8*>(&As[r * 32 + ((lk ^ ((r >> 1) & 3)) * 8)]);
        }
        #pragma unroll
        for (int n = 0; n < 4; ++n) {
            int r = wc * 64 + n * 16 + lr;
            bfr[n] = *reinterpret_cast<const bf16x8*>(&Bs[r * 32 + ((lk ^ ((r >> 1) & 3)) * 8)]);
        }
        #pragma unroll
        for (int m = 0; m < 4; ++m)
            #pragma unroll
            for (int n = 0; n < 4; ++n)
                acc[m][n] = __builtin_amdgcn_mfma_f32_16x16x32_bf16(af[m], bfr[n], acc[m][n], 0, 0, 0);
        __syncthreads();
    }

    #pragma unroll
    for (int n = 0; n < 4; ++n) {
        int col = bn + wc * 64 + n * 16 + lr;
        if (col >= N) continue;
        float bsv = bias ? bias[col] : 0.0f;
        #pragma unroll
        for (int m = 0; m < 4; ++m) {
            #pragma unroll
            for (int r4 = 0; r4 < 4; ++r4) {
                int row = bm + wr * 64 + m * 16 + lk * 4 + r4;
                float o = acc[m][n][r4] + bsv;
                size_t idx = (size_t)row * N + col;
                if (EPI == 0)      Cf[idx] = o;
                else if (EPI == 1) Cb[idx] = f2b(gelu_exact(o));
                else if (EPI == 3) Cf[idx] += o;
                else if (EPI == 4) Cb[idx] = f2b(o);
            }
        }
    }
}

// ---------------------------------------------------------------------------
// 64x64 tile, 4 waves (2x2), each wave 32x32 = 2x2 frags. For low-block GEMMs.
// EPI==2: alpha = sigmoid(acc+bias); Cf(x) = x + alpha*h + (1-alpha)*g (N==D).
// ---------------------------------------------------------------------------
template<int EPI>
__global__ __launch_bounds__(256) void mgemm64_k(
    const ushort* __restrict__ A, const ushort* __restrict__ W,
    const float* __restrict__ bias, float* __restrict__ Cf,
    const float* __restrict__ hbuf, const float* __restrict__ gbuf,
    int M, int N, int K)
{
    __shared__ ushort As[64 * 32];
    __shared__ ushort Bs[64 * 32];
    const int tid = threadIdx.x;
    const int lane = tid & 63;
    const int w = tid >> 6;
    const int wr = w >> 1, wc = w & 1;
    const int lr = lane & 15, lk = lane >> 4;
    const int bm = blockIdx.x * 64, bn = blockIdx.y * 64;
    const int srow = lane >> 2;
    const int scol = (((lane & 3) ^ ((srow >> 1) & 3)) * 8);

    f32x4 acc[2][2] = {};

    for (int k0 = 0; k0 < K; k0 += 32) {
        {
            int r = w * 16 + srow;
            GLOAD16(A + (size_t)(bm + r) * K + (k0 + scol), &As[(w * 16) * 32]);
        }
        {
            int r = bn + w * 16 + srow;
            if (r > N - 1) r = N - 1;
            GLOAD16(W + (size_t)r * K + (k0 + scol), &Bs[(w * 16) * 32]);
        }
        __syncthreads();
        bf16x8 af[2], bfr[2];
        #pragma unroll
        for (int m = 0; m < 2; ++m) {
            int r = wr * 32 + m * 16 + lr;
            af[m] = *reinterpret_cast<const bf16x8*>(&As[r * 32 + ((lk ^ ((r >> 1) & 3)) * 8)]);
        }
        #pragma unroll
        for (int n = 0; n < 2; ++n) {
            int r = wc * 32 + n * 16 + lr;
            bfr[n] = *reinterpret_cast<const bf16x8*>(&Bs[r * 32 + ((lk ^ ((r >> 1) & 3)) * 8)]);
        }
        #pragma unroll
        for (int m = 0; m < 2; ++m)
            #pragma unroll
            for (int n = 0; n < 2; ++n)
                acc[m][n] = __builtin_amdgcn_mfma_f32_16x16x32_bf16(af[m], bfr[n], acc[m][n], 0, 0, 0);
        __syncthreads();
    }

    #pragma unroll
    for (int n = 0; n < 2; ++n) {
        int col = bn + wc * 32 + n * 16 + lr;
        if (col >= N) continue;
        float bsv = bias ? bias[col] : 0.0f;
        #pragma unroll
        for (int m = 0; m < 2; ++m) {
            #pragma unroll
            for (int r4 = 0; r4 < 4; ++r4) {
                int row = bm + wr * 32 + m * 16 + lk * 4 + r4;
                float o = acc[m][n][r4] + bsv;
                size_t idx = (size_t)row * N + col;
                if (EPI == 2) {
                    float a = sigmoid_f(o);
                    Cf[idx] = Cf[idx] + a * hbuf[idx] + (1.0f - a) * gbuf[idx];
                } else if (EPI == 3) {
                    Cf[idx] += o;
                }
            }
        }
    }
}

// ---------------------------------------------------------------------------
// Small f32 GEMM (red projection only, N=24): C = A[M,K]·W[N,K]^T + bias
// ---------------------------------------------------------------------------
#define TILE 64
#define BK 16
__global__ __launch_bounds__(256) void gemm_f32_k(
    const float* __restrict__ A, const float* __restrict__ W,
    const float* __restrict__ bias, float* __restrict__ C,
    int M, int N, int K)
{
    __shared__ float As[TILE][BK + 1];
    __shared__ float Bs[TILE][BK + 1];
    const int bm = blockIdx.y * TILE;
    const int bn = blockIdx.x * TILE;
    const int tid = threadIdx.x;
    const int tx = tid & 15;
    const int ty = tid >> 4;
    const int lrow = tid >> 2;
    const int lcol = (tid & 3) << 2;

    float acc[4][4] = {};

    for (int k0 = 0; k0 < K; k0 += BK) {
        {
            float4 v = make_float4(0.f, 0.f, 0.f, 0.f);
            int gr = bm + lrow, gc = k0 + lcol;
            if (gr < M && gc < K)
                v = *reinterpret_cast<const float4*>(A + (size_t)gr * K + gc);
            As[lrow][lcol + 0] = v.x; As[lrow][lcol + 1] = v.y;
            As[lrow][lcol + 2] = v.z; As[lrow][lcol + 3] = v.w;
        }
        {
            float4 v = make_float4(0.f, 0.f, 0.f, 0.f);
            int gr = bn + lrow, gc = k0 + lcol;
            if (gr < N && gc < K)
                v = *reinterpret_cast<const float4*>(W + (size_t)gr * K + gc);
            Bs[lrow][lcol + 0] = v.x; Bs[lrow][lcol + 1] = v.y;
            Bs[lrow][lcol + 2] = v.z; Bs[lrow][lcol + 3] = v.w;
        }
        __syncthreads();
        #pragma unroll
        for (int k = 0; k < BK; ++k) {
            float a0 = As[ty * 4 + 0][k], a1 = As[ty * 4 + 1][k];
            float a2 = As[ty * 4 + 2][k], a3 = As[ty * 4 + 3][k];
            float b0 = Bs[tx * 4 + 0][k], b1 = Bs[tx * 4 + 1][k];
            float b2 = Bs[tx * 4 + 2][k], b3 = Bs[tx * 4 + 3][k];
            acc[0][0] += a0 * b0; acc[0][1] += a0 * b1; acc[0][2] += a0 * b2; acc[0][3] += a0 * b3;
            acc[1][0] += a1 * b0; acc[1][1] += a1 * b1; acc[1][2] += a1 * b2; acc[1][3] += a1 * b3;
            acc[2][0] += a2 * b0; acc[2][1] += a2 * b1; acc[2][2] += a2 * b2; acc[2][3] += a2 * b3;
            acc[3][0] += a3 * b0; acc[3][1] += a3 * b1; acc[3][2] += a3 * b2; acc[3][3] += a3 * b3;
        }
        __syncthreads();
    }
    #pragma unroll
    for (int i = 0; i < 4; ++i) {
        int row = bm + ty * 4 + i;
        if (row >= M) continue;
        #pragma unroll
        for (int j = 0; j < 4; ++j) {
            int col = bn + tx * 4 + j;
            if (col >= N) continue;
            C[(size_t)row * N + col] = acc[i][j] + (bias ? bias[col] : 0.0f);
        }
    }
}

// ---------------------------------------------------------------------------
__global__ __launch_bounds__(256) void embed_k(
    const int* __restrict__ ids, const float* __restrict__ tok,
    const float* __restrict__ pos, float* __restrict__ x)
{
    int idx = blockIdx.x * 256 + threadIdx.x;
    if (idx >= M_ * D_) return;
    int row = idx / D_;
    int d = idx - row * D_;
    int l = row & (L_ - 1);
    x[idx] = tok[(size_t)ids[row] * D_ + d] + pos[(size_t)l * D_ + d];
}

__global__ __launch_bounds__(256) void cvt_k(
    const float* __restrict__ src, ushort* __restrict__ dst, int n)
{
    int idx = blockIdx.x * 256 + threadIdx.x;
    if (idx < n) dst[idx] = f2b(src[idx]);
}

// per-layer weight conversion (gp1 padded 276->288, gp2, gate, fc1, fc2)
#define WC_G1  73728
#define WC_G2  (WC_G1 + 163840)
#define WC_GT  (WC_G2 + 819200)
#define WC_F1  (WC_GT + 1638400)
#define WC_F2  (WC_F1 + 1638400)
__global__ __launch_bounds__(256) void wconv_k(
    const float* __restrict__ g1, const float* __restrict__ g2,
    const float* __restrict__ gt, const float* __restrict__ f1,
    const float* __restrict__ f2, ushort* __restrict__ wb)
{
    int idx = blockIdx.x * 256 + threadIdx.x;
    if (idx < WC_G1) {
        int row = idx / PLUP_, c = idx - row * PLUP_;
        wb[idx] = (c < PLU_) ? f2b(g1[row * PLU_ + c]) : (ushort)0;
    } else if (idx < WC_G2) {
        wb[idx] = f2b(g2[idx - WC_G1]);
    } else if (idx < WC_GT) {
        wb[idx] = f2b(gt[idx - WC_G2]);
    } else if (idx < WC_F1) {
        wb[idx] = f2b(f1[idx - WC_GT]);
    } else if (idx < WC_F2) {
        wb[idx] = f2b(f2[idx - WC_F1]);
    }
}

// ---------------------------------------------------------------------------
__global__ __launch_bounds__(128) void ln_k(
    const float* __restrict__ x, const float* __restrict__ w,
    const float* __restrict__ b, float* __restrict__ outf,
    ushort* __restrict__ outb, int bstride)
{
    int row = blockIdx.x;
    int tid = threadIdx.x;
    const float* xr = x + (size_t)row * D_;
    float v[5];
    float sum = 0.f, sumsq = 0.f;
    #pragma unroll
    for (int t = 0; t < 5; ++t) {
        v[t] = xr[tid + t * 128];
        sum += v[t]; sumsq += v[t] * v[t];
    }
    #pragma unroll
    for (int off = 32; off > 0; off >>= 1) {
        sum += __shfl_down(sum, off);
        sumsq += __shfl_down(sumsq, off);
    }
    __shared__ float s0[2], s1[2];
    if ((tid & 63) == 0) { s0[tid >> 6] = sum; s1[tid >> 6] = sumsq; }
    __syncthreads();
    float m = (s0[0] + s0[1]) * (1.0f / D_);
    float var = (s1[0] + s1[1]) * (1.0f / D_) - m * m;
    float inv = rsqrtf(var + LN_EPS_);
    #pragma unroll
    for (int t = 0; t < 5; ++t) {
        int d = tid + t * 128;
        float o = (v[t] - m) * inv * w[d] + b[d];
        if (outf) outf[(size_t)row * D_ + d] = o;
        if (outb) outb[(size_t)row * bstride + d] = f2b(o);
    }
}

// ---------------------------------------------------------------------------
__global__ __launch_bounds__(128) void plucker7_k(
    const float* __restrict__ z, ushort* __restrict__ pb)
{
    int oi = blockIdx.y;
    int delta = 1 << oi;
    int row = blockIdx.x;
    int l = row & (L_ - 1);
    int tid = threadIdx.x;
    ushort* out = pb + ((size_t)oi * M_ + row) * PLUP_;
    if (l < delta) {
        for (int idx = tid; idx < PLUP_; idx += 128) out[idx] = 0;
        return;
    }
    __shared__ float zc[R_], zp[R_];
    if (tid < R_) {
        zc[tid] = z[(size_t)row * R_ + tid];
        zp[tid] = z[(size_t)(row - delta) * R_ + tid];
    }
    __syncthreads();
    float vals[3];
    float ss = 0.f;
    #pragma unroll
    for (int t = 0; t < 3; ++t) {
        int idx = tid + t * 128;
        float val = 0.f;
        if (idx < PLU_) {
            int i = 0, rem = idx;
            while (rem >= 23 - i) { rem -= 23 - i; ++i; }
            int j = i + 1 + rem;
            val = zp[i] * zc[j] - zp[j] * zc[i];
        }
        vals[t] = val;
        ss += val * val;
    }
    #pragma unroll
    for (int off = 32; off > 0; off >>= 1) ss += __shfl_down(ss, off);
    __shared__ float wsum[2];
    if ((tid & 63) == 0) wsum[tid >> 6] = ss;
    __syncthreads();
    float inv = 1.0f / fmaxf(sqrtf(wsum[0] + wsum[1]), EPS_);
    #pragma unroll
    for (int t = 0; t < 3; ++t) {
        int idx = tid + t * 128;
        if (idx < PLUP_) out[idx] = (idx < PLU_) ? f2b(vals[t] * inv) : (ushort)0;
    }
}

// ---------------------------------------------------------------------------
// g = (sum over valid deltas of bf16 gbig) / max(count,1); writes f32 g + bf16 hg
// ---------------------------------------------------------------------------
__global__ __launch_bounds__(256) void greduce_k(
    const ushort* __restrict__ gbigb, float* __restrict__ g,
    ushort* __restrict__ hgb)
{
    int idx = blockIdx.x * 256 + threadIdx.x;
    if (idx >= M_ * D_) return;
    int row = idx / D_;
    int d = idx - row * D_;
    int l = row & (L_ - 1);
    float s = 0.f;
    int c = 0;
    #pragma unroll
    for (int oi = 0; oi < 7; ++oi) {
        if (l >= (1 << oi)) {
            s += b2f(gbigb[(size_t)oi * M_ * D_ + idx]);
            ++c;
        }
    }
    float gv = s / (float)max(c, 1);
    g[idx] = gv;
    hgb[(size_t)row * (2 * D_) + D_ + d] = f2b(gv);
}

// ---------------------------------------------------------------------------
static void mg128(int epi, const ushort* A, const ushort* W, const float* bias,
                  float* Cf, ushort* Cb, int M, int N, int K, hipStream_t s)
{
    dim3 grid(M / 128, (N + 127) / 128), block(256);
    if (epi == 0)      mgemm128_k<0><<<grid, block, 0, s>>>(A, W, bias, Cf, Cb, M, N, K);
    else if (epi == 1) mgemm128_k<1><<<grid, block, 0, s>>>(A, W, bias, Cf, Cb, M, N, K);
    else               mgemm128_k<4><<<grid, block, 0, s>>>(A, W, bias, Cf, Cb, M, N, K);
}

static void mg64(int epi, const ushort* A, const ushort* W, const float* bias,
                 float* Cf, const float* h, const float* g, int M, int N, int K,
                 hipStream_t s)
{
    dim3 grid(M / 64, (N + 63) / 64), block(256);
    if (epi == 2) mgemm64_k<2><<<grid, block, 0, s>>>(A, W, bias, Cf, h, g, M, N, K);
    else          mgemm64_k<3><<<grid, block, 0, s>>>(A, W, bias, Cf, h, g, M, N, K);
}

extern "C" void kernel_launch(void* const* d_in, const int* in_sizes, int n_in,
                              void* d_out, int out_size, void* d_ws, size_t ws_size,
                              hipStream_t stream)
{
    const int*   ids   = (const int*)d_in[0];
    const float* tok   = (const float*)d_in[1];
    const float* pos   = (const float*)d_in[2];
    const float* ln1w  = (const float*)d_in[3];
    const float* ln1b  = (const float*)d_in[4];
    const float* redw  = (const float*)d_in[5];
    const float* redb  = (const float*)d_in[6];
    const float* gp1w  = (const float*)d_in[7];
    const float* gp1b  = (const float*)d_in[8];
    const float* gp2w  = (const float*)d_in[9];
    const float* gp2b  = (const float*)d_in[10];
    const float* gatew = (const float*)d_in[11];
    const float* gateb = (const float*)d_in[12];
    const float* ln2w  = (const float*)d_in[13];
    const float* ln2b  = (const float*)d_in[14];
    const float* fc1w  = (const float*)d_in[15];
    const float* fc1b  = (const float*)d_in[16];
    const float* fc2w  = (const float*)d_in[17];
    const float* fc2b  = (const float*)d_in[18];
    const float* fnw   = (const float*)d_in[19];
    const float* fnb   = (const float*)d_in[20];
    float* out = (float*)d_out;

    const size_t MD = (size_t)M_ * D_;
    float* ws = (float*)d_ws;
    float* x = ws;                       // MD
    float* h = x + MD;                   // MD
    float* g = h + MD;                   // MD
    float* z = g + MD;                   // M_*R_
    ushort* gbigb = (ushort*)(z + (size_t)M_ * R_);       // 7*MD
    ushort* pb    = gbigb + 7 * MD;                       // 7*M_*288
    ushort* c1b   = pb + (size_t)7 * M_ * PLUP_;          // 7*M_*256
    ushort* hgb   = c1b + (size_t)7 * M_ * DG_;           // M_*1280
    ushort* h2b   = hgb + (size_t)M_ * 2 * D_;            // M_*640
    ushort* ffb   = h2b + MD;                             // M_*2560
    ushort* xnb   = ffb + (size_t)M_ * DF_;               // M_*640
    ushort* tokb  = xnb + MD;                             // V_*640
    ushort* wb    = tokb + (size_t)V_ * D_;               // 4,333,568

    const int ELT_GRID = (M_ * D_ + 255) / 256;

    embed_k<<<ELT_GRID, 256, 0, stream>>>(ids, tok, pos, x);
    cvt_k<<<(V_ * D_ + 255) / 256, 256, 0, stream>>>(tok, tokb, V_ * D_);

    for (int l = 0; l < NL_; ++l) {
        wconv_k<<<(WC_F2 + 255) / 256, 256, 0, stream>>>(
            gp1w + (size_t)l * DG_ * PLU_, gp2w + (size_t)l * D_ * DG_,
            gatew + (size_t)l * D_ * 2 * D_, fc1w + (size_t)l * DF_ * D_,
            fc2w + (size_t)l * D_ * DF_, wb);
        ln_k<<<M_, 128, 0, stream>>>(x, ln1w + (size_t)l * D_, ln1b + (size_t)l * D_,
                                     h, hgb, 2 * D_);
        {
            dim3 grid((R_ + TILE - 1) / TILE, (M_ + TILE - 1) / TILE), block(256);
            gemm_f32_k<<<grid, block, 0, stream>>>(h, redw + (size_t)l * R_ * D_,
                                                   redb + (size_t)l * R_, z, M_, R_, D_);
        }
        plucker7_k<<<dim3(M_, 7), 128, 0, stream>>>(z, pb);
        mg128(1, pb, wb, gp1b + (size_t)l * DG_, nullptr, c1b, 7 * M_, DG_, PLUP_, stream);
        mg128(4, c1b, wb + WC_G1, gp2b + (size_t)l * D_, nullptr, gbigb, 7 * M_, D_, DG_, stream);
        greduce_k<<<ELT_GRID, 256, 0, stream>>>(gbigb, g, hgb);
        // gate GEMM fused with x-update: x = x + a*h + (1-a)*g
        mg64(2, hgb, wb + WC_G2, gateb + (size_t)l * D_, x, h, g, M_, D_, 2 * D_, stream);
        ln_k<<<M_, 128, 0, stream>>>(x, ln2w + (size_t)l * D_, ln2b + (size_t)l * D_,
                                     nullptr, h2b, D_);
        mg128(1, h2b, wb + WC_GT, fc1b + (size_t)l * DF_, nullptr, ffb, M_, DF_, D_, stream);
        mg64(3, ffb, wb + WC_F1, fc2b + (size_t)l * D_, x, nullptr, nullptr, M_, D_, DF_, stream);
    }
    ln_k<<<M_, 128, 0, stream>>>(x, fnw, fnb, nullptr, xnb, D_);
    mg128(0, xnb, tokb, nullptr, out, nullptr, M_, V_, D_, stream);
}